// Round 5
// baseline (347.437 us; speedup 1.0000x reference)
//
#include <hip/hip_runtime.h>

#define NEG_SLOPE 0.01f
#define BSHIFT 8          // nodes per dst-bucket = 256
#define BMASK 255
#define BMAX 512          // bucket capacity (supports N <= 131072)
#define HB 256            // histogram blocks (partials, no pre-zeroing needed)

typedef __attribute__((ext_vector_type(8))) short bf16x8;
typedef __attribute__((ext_vector_type(4))) float f32x4;
typedef __attribute__((ext_vector_type(2))) float f32x2;
typedef __attribute__((ext_vector_type(4))) unsigned u32x4;

// fp32 -> bf16 (RNE, normals only — fine for this data)
static __device__ inline unsigned short f2b(float f) {
    unsigned u = __builtin_bit_cast(unsigned, f);
    return (unsigned short)((u + 0x7FFF + ((u >> 16) & 1)) >> 16);
}
static __device__ inline float b2f_lo(unsigned u) {
    return __builtin_bit_cast(float, u << 16);
}
static __device__ inline float b2f_hi(unsigned u) {
    return __builtin_bit_cast(float, u & 0xFFFF0000u);
}

// ---------------------------------------------------------------------------
// Fused front kernel:
//   blocks [0, nf4)          : feat fp32 -> bf16 (vectorized x4)
//   blocks [nf4, nf4+64)     : W1/W2 -> Wt (transposed bf16)
//   blocks [nf4+64, +HB)     : dst-bucket histogram -> per-block partials
//                              (plain stores, so no bcnt zeroing dispatch)
// ---------------------------------------------------------------------------
__global__ __launch_bounds__(256) void front_kernel(const float* __restrict__ feat,
                                                    unsigned short* __restrict__ featb,
                                                    long long nfeat,
                                                    const float* __restrict__ W1,
                                                    const float* __restrict__ W2,
                                                    unsigned short* __restrict__ Wt1,
                                                    unsigned short* __restrict__ Wt2,
                                                    const int* __restrict__ dst,
                                                    int* __restrict__ bpart,
                                                    int E, int B, int nf4) {
    const int bx = blockIdx.x;
    const int t = threadIdx.x;
    if (bx < nf4) {
        long long i = ((long long)bx * 256 + t) * 4;
        if (i < nfeat) {
            float4 v = *(const float4*)(feat + i);
            ushort4 o;
            o.x = f2b(v.x); o.y = f2b(v.y); o.z = f2b(v.z); o.w = f2b(v.w);
            *(ushort4*)(featb + i) = o;
        }
        return;
    }
    const int bx2 = bx - nf4;
    if (bx2 < 64) {
        int i = bx2 * 256 + t;            // 0..16383
        int n = i & 127, k = i >> 7;
        Wt1[n * 128 + k] = f2b(W1[k * 128 + n]);
        Wt2[n * 128 + k] = f2b(W2[k * 128 + n]);
        return;
    }
    // histogram partials
    const int hb = bx2 - 64;              // 0..HB-1
    __shared__ int h[BMAX];
    for (int i = t; i < BMAX; i += 256) h[i] = 0;
    __syncthreads();
    const int stride = HB * 256;
    for (int e = hb * 256 + t; e < E; e += stride)
        atomicAdd(&h[dst[e] >> BSHIFT], 1);
    __syncthreads();
    for (int i = t; i < B; i += 256) bpart[i * HB + hb] = h[i];
}

// ---------------------------------------------------------------------------
// Sum histogram partials + exclusive scan over buckets.
// bcursor consumed by bscatter; bstart persists for bfinal.
// ---------------------------------------------------------------------------
__global__ __launch_bounds__(512) void bscan_kernel(const int* __restrict__ bpart,
                                                    int* __restrict__ bcursor,
                                                    int* __restrict__ bstart, int B) {
    __shared__ int sh[512];
    const int t = threadIdx.x;
    int v = 0;
    if (t < B) {
        const int4* p4 = (const int4*)(bpart + t * HB);   // 1 KB contiguous/thread
#pragma unroll 8
        for (int j = 0; j < HB / 4; ++j) {
            int4 q = p4[j];
            v += q.x + q.y + q.z + q.w;
        }
    }
    sh[t] = v;
    __syncthreads();
    for (int d = 1; d < 512; d <<= 1) {
        int u = (t >= d) ? sh[t - d] : 0;
        __syncthreads();
        sh[t] += u;
        __syncthreads();
    }
    if (t < B) {
        int excl = sh[t] - v;
        bcursor[t] = excl;
        bstart[t] = excl;
    }
    if (t == B - 1) bstart[B] = sh[t];
}

// Partition edges into dst-buckets. Packed: src (24 bits) | local-dst (8 bits).
__global__ __launch_bounds__(256) void bscatter_kernel(const int* __restrict__ src,
                                                       const int* __restrict__ dst,
                                                       int* __restrict__ bcursor,
                                                       unsigned* __restrict__ pairs,
                                                       int E, int B) {
    __shared__ int h[BMAX];
    __shared__ int base[BMAX];
    const int t = threadIdx.x;
    for (int i = t; i < B; i += 256) h[i] = 0;
    __syncthreads();
    const int chunk = (E + gridDim.x - 1) / gridDim.x;
    const int e0 = blockIdx.x * chunk;
    const int e1 = min(e0 + chunk, E);
    for (int e = e0 + t; e < e1; e += 256)
        atomicAdd(&h[dst[e] >> BSHIFT], 1);
    __syncthreads();
    for (int i = t; i < B; i += 256) {
        int c = h[i];
        base[i] = c ? atomicAdd(&bcursor[i], c) : 0;
    }
    __syncthreads();
    for (int i = t; i < B; i += 256) h[i] = base[i];
    __syncthreads();
    for (int e = e0 + t; e < e1; e += 256) {
        int d = dst[e];
        int pos = atomicAdd(&h[d >> BSHIFT], 1);
        pairs[pos] = (unsigned)src[e] | ((unsigned)(d & BMASK) << 24);
    }
}

// ---------------------------------------------------------------------------
// Per-bucket finalize: histogram 256 local dsts -> LDS scan -> node offsets +
// scatter src into csr (contiguous per-bucket window, LDS atomics only).
// ---------------------------------------------------------------------------
__global__ __launch_bounds__(256) void bfinal_kernel(const unsigned* __restrict__ pairs,
                                                     const int* __restrict__ bstart,
                                                     int* __restrict__ offsets,
                                                     int* __restrict__ csr,
                                                     int N, int E) {
    __shared__ int h[256];
    __shared__ int cur[256];
    const int b = blockIdx.x;
    const int t = threadIdx.x;
    const int e0 = bstart[b], e1 = bstart[b + 1];
    h[t] = 0;
    __syncthreads();
    for (int e = e0 + t; e < e1; e += 256)
        atomicAdd(&h[pairs[e] >> 24], 1);
    __syncthreads();
    int v = h[t];
    for (int d = 1; d < 256; d <<= 1) {
        int u = (t >= d) ? h[t - d] : 0;
        __syncthreads();
        h[t] += u;
        __syncthreads();
    }
    const int base = e0 + (h[t] - v);   // exclusive prefix within bucket
    const int node = (b << BSHIFT) + t;
    if (node < N) offsets[node] = base;
    if (b == (int)gridDim.x - 1 && t == 255) offsets[N] = E;
    cur[t] = base;
    __syncthreads();
    for (int e = e0 + t; e < e1; e += 256) {
        unsigned pr = pairs[e];
        int pos = atomicAdd(&cur[pr >> 24], 1);
        csr[pos] = (int)(pr & 0xFFFFFFu);
    }
}

// ---------------------------------------------------------------------------
// Aggregate: Hb[n][:] = bf16( (xb[n][:] + sum_neighbors xb[s][:]) / (deg+1) )
//
// One wave per node; 4 lane-groups of 16, one 256B row per group per gather
// instruction (1 KB / instr, 64 useful lanes). ADDRESS-RATE economy (~4
// lane-addrs/cy/CU model from r4 counters): ALL index traffic moved to the
// SCALAR path — node is wave-uniform, so offsets[nu] and csr[start+k] are
// uniform-address loads (s_load, no TA lanes). Gather addresses built from
// SGPR indices (cndmask by group). Exact gather count (wave-uniform branches,
// no junk loads, no clamps); 4 gathers (4 KB) in flight via inline-asm
// global_load_dwordx4 (compiler cannot re-serialize). Self-gather is
// exec-masked to group 0 (16 lane-addrs, not 64).
// ---------------------------------------------------------------------------
static __device__ inline f32x2 up2(unsigned u) {
    return (f32x2){ b2f_lo(u), b2f_hi(u) };
}

#define GATHER(dst, off) \
    asm volatile("global_load_dwordx4 %0, %1, %2" : "=v"(dst) : "v"(off), "s"(xc))
#define ACC4(u) do { A0 += up2((u).x); A1 += up2((u).y); \
                     A2 += up2((u).z); A3 += up2((u).w); } while (0)
#define ACCM(u, mk) do { \
    A0 += up2((u).x & (mk)); A1 += up2((u).y & (mk)); \
    A2 += up2((u).z & (mk)); A3 += up2((u).w & (mk)); } while (0)

static __device__ __forceinline__ unsigned rowsel(int g, unsigned poff,
                                                  int i0, int i1, int i2, int i3) {
    int s01 = (g & 1) ? i1 : i0;
    int s23 = (g & 1) ? i3 : i2;
    int s = (g & 2) ? s23 : s01;
    return ((unsigned)s << 8) | poff;
}

__global__ __launch_bounds__(256) void aggregate_kernel(const unsigned short* __restrict__ xb,
                                                        const int* __restrict__ offsets,
                                                        const int* __restrict__ csr,
                                                        unsigned short* __restrict__ Hb,
                                                        int N) {
    const int node = (blockIdx.x * blockDim.x + threadIdx.x) >> 6;
    if (node >= N) return;
    const int lane = threadIdx.x & 63;
    const int g = lane >> 4;                              // neighbor slot 0..3
    const unsigned poff = (unsigned)((lane & 15) << 4);   // 16B chunk in row
    const char* __restrict__ xc = (const char*)xb;

    // wave-uniform node -> scalar offsets/csr loads (SMEM path, zero TA lanes)
    const int nu = __builtin_amdgcn_readfirstlane(node);
    const int start = __builtin_amdgcn_readfirstlane(offsets[nu]);
    const int end   = __builtin_amdgcn_readfirstlane(offsets[nu + 1]);
    const int deg   = end - start;
    const int rounds = deg >> 2;
    const int tailn  = deg & 3;

    // self gather: group 0 only (16 lane-addrs); consumed post-reduce
    u32x4 vs = (u32x4){0, 0, 0, 0};
    if (g == 0) GATHER(vs, ((unsigned)nu << 8) | poff);

    f32x2 A0 = {0.f, 0.f}, A1 = {0.f, 0.f}, A2 = {0.f, 0.f}, A3 = {0.f, 0.f};

    int r = 0;
    while (r + 4 <= rounds) {             // wave-uniform
        const int p = start + (r << 2);
        int i0  = csr[p +  0], i1  = csr[p +  1], i2  = csr[p +  2], i3  = csr[p +  3];
        int i4  = csr[p +  4], i5  = csr[p +  5], i6  = csr[p +  6], i7  = csr[p +  7];
        int i8  = csr[p +  8], i9  = csr[p +  9], i10 = csr[p + 10], i11 = csr[p + 11];
        int i12 = csr[p + 12], i13 = csr[p + 13], i14 = csr[p + 14], i15 = csr[p + 15];
        unsigned a0 = rowsel(g, poff, i0,  i1,  i2,  i3);
        unsigned a1 = rowsel(g, poff, i4,  i5,  i6,  i7);
        unsigned a2 = rowsel(g, poff, i8,  i9,  i10, i11);
        unsigned a3 = rowsel(g, poff, i12, i13, i14, i15);
        __builtin_amdgcn_sched_barrier(0);
        u32x4 v0, v1, v2, v3;
        GATHER(v0, a0); GATHER(v1, a1); GATHER(v2, a2); GATHER(v3, a3);
        asm volatile("s_waitcnt vmcnt(0)" ::: "memory");
        __builtin_amdgcn_sched_barrier(0);
        ACC4(v0); ACC4(v1); ACC4(v2); ACC4(v3);
        r += 4;
    }

    // remainder rounds (0..3) + tail, exact counts, wave-uniform branches
    const int rr = rounds - r;
    const int p = start + (r << 2);
    u32x4 v0, v1, v2, vt;
    if (rr >= 1) {
        int i0 = csr[p + 0], i1 = csr[p + 1], i2 = csr[p + 2], i3 = csr[p + 3];
        GATHER(v0, rowsel(g, poff, i0, i1, i2, i3));
    }
    if (rr >= 2) {
        int i0 = csr[p + 4], i1 = csr[p + 5], i2 = csr[p + 6], i3 = csr[p + 7];
        GATHER(v1, rowsel(g, poff, i0, i1, i2, i3));
    }
    if (rr >= 3) {
        int i0 = csr[p + 8], i1 = csr[p + 9], i2 = csr[p + 10], i3 = csr[p + 11];
        GATHER(v2, rowsel(g, poff, i0, i1, i2, i3));
    }
    const unsigned mt = (g < tailn) ? ~0u : 0u;
    if (tailn) {
        const int q = start + (rounds << 2);
        int t0 = csr[q];
        int t1 = (tailn > 1) ? csr[q + 1] : t0;
        int t2 = (tailn > 2) ? csr[q + 2] : t0;
        GATHER(vt, rowsel(g, poff, t0, t1, t2, t0));
    }
    asm volatile("s_waitcnt vmcnt(0)" ::: "memory");
    __builtin_amdgcn_sched_barrier(0);
    if (rr >= 1) ACC4(v0);
    if (rr >= 2) ACC4(v1);
    if (rr >= 3) ACC4(v2);
    if (tailn) ACCM(vt, mt);

    // combine the 4 lane-groups: butterfly leaves full sum in every lane
    float a[8];
    a[0] = A0.x; a[1] = A0.y; a[2] = A1.x; a[3] = A1.y;
    a[4] = A2.x; a[5] = A2.y; a[6] = A3.x; a[7] = A3.y;
#pragma unroll
    for (int i = 0; i < 8; ++i) {
        a[i] += __shfl_xor(a[i], 16);
        a[i] += __shfl_xor(a[i], 32);
    }
    // self term (group 0 only holds it; group 0 is the storing group)
    a[0] += b2f_lo(vs.x); a[1] += b2f_hi(vs.x);
    a[2] += b2f_lo(vs.y); a[3] += b2f_hi(vs.y);
    a[4] += b2f_lo(vs.z); a[5] += b2f_hi(vs.z);
    a[6] += b2f_lo(vs.w); a[7] += b2f_hi(vs.w);

    const float inv = 1.0f / (float)(deg + 1);
    if (g == 0) {
        uint4 o;
        o.x = (unsigned)f2b(a[0] * inv) | ((unsigned)f2b(a[1] * inv) << 16);
        o.y = (unsigned)f2b(a[2] * inv) | ((unsigned)f2b(a[3] * inv) << 16);
        o.z = (unsigned)f2b(a[4] * inv) | ((unsigned)f2b(a[5] * inv) << 16);
        o.w = (unsigned)f2b(a[6] * inv) | ((unsigned)f2b(a[7] * inv) << 16);
        *(uint4*)((char*)Hb + (((unsigned)node << 8) | poff)) = o;
    }
}

// ---------------------------------------------------------------------------
// MFMA GEMM: out[r][c] = leaky( sum_k H[r][k] * W[k][c] + b[c] )
// 128 rows x 128 cols per block, 256 threads = 4 waves; wave w covers rows
// w*32..w*32+31 as 2 row-tiles x 8 col-tiles of 16x16x32 bf16 MFMA.
// W staged in LDS (reused by all 4 waves, XOR-swizzled, conflict-free b128);
// A-fragments stream STRAIGHT FROM GLOBAL (fully coalesced, used once).
// ---------------------------------------------------------------------------
template <bool OUT_BF16>
__global__ __launch_bounds__(256) void gemm_mfma(const unsigned short* __restrict__ Hb,
                                                 const unsigned short* __restrict__ Wt,
                                                 const float* __restrict__ b,
                                                 void* __restrict__ outv, int N) {
    __shared__ unsigned short Wa[128 * 128];  // 32 KB
    const int tid = threadIdx.x;
    const int row0 = blockIdx.x * 128;

    // Stage Wa (Wt is [n][k] bf16, 2048 16B chunks, swizzled)
#pragma unroll
    for (int it = 0; it < 8; ++it) {
        int idx = it * 256 + tid;
        int r = idx >> 4, c = idx & 15;
        uint4 v = *(const uint4*)(Wt + r * 128 + c * 8);
        *(uint4*)(Wa + r * 128 + ((c ^ (r & 15)) << 3)) = v;
    }
    __syncthreads();

    const int w = tid >> 6;
    const int lane = tid & 63;
    const int m = lane & 15;   // A row-in-tile / B col-in-tile / C col
    const int q = lane >> 4;   // quad

    // A rows for this lane (clamped; OOB rows never stored)
    const int r0 = row0 + w * 32 + m;
    const size_t ar0 = (size_t)min(r0, N - 1) * 128;
    const size_t ar1 = (size_t)min(r0 + 16, N - 1) * 128;

    f32x4 acc[2][8];
#pragma unroll
    for (int rt = 0; rt < 2; ++rt)
#pragma unroll
        for (int ct = 0; ct < 8; ++ct) acc[rt][ct] = (f32x4){0.f, 0.f, 0.f, 0.f};

#pragma unroll
    for (int kk = 0; kk < 4; ++kk) {
        const int chunk = kk * 4 + q;  // this lane's 16B chunk (8 bf16 of k)
        bf16x8 af0 = *(const bf16x8*)(Hb + ar0 + chunk * 8);
        bf16x8 af1 = *(const bf16x8*)(Hb + ar1 + chunk * 8);
#pragma unroll
        for (int ct = 0; ct < 8; ++ct) {
            int n = ct * 16 + m;
            bf16x8 bfr = *(const bf16x8*)(Wa + n * 128 + ((chunk ^ (n & 15)) << 3));
            acc[0][ct] = __builtin_amdgcn_mfma_f32_16x16x32_bf16(af0, bfr, acc[0][ct], 0, 0, 0);
            acc[1][ct] = __builtin_amdgcn_mfma_f32_16x16x32_bf16(af1, bfr, acc[1][ct], 0, 0, 0);
        }
    }

    // Epilogue: bias + leaky-relu, store (fp32 or bf16)
#pragma unroll
    for (int ct = 0; ct < 8; ++ct) {
        const float bias = b[ct * 16 + m];
        const int gcol = ct * 16 + m;
#pragma unroll
        for (int rt = 0; rt < 2; ++rt) {
#pragma unroll
            for (int reg = 0; reg < 4; ++reg) {
                int grow = row0 + w * 32 + rt * 16 + q * 4 + reg;
                if (grow < N) {
                    float v = acc[rt][ct][reg] + bias;
                    v = v > 0.f ? v : v * NEG_SLOPE;
                    if (OUT_BF16)
                        ((unsigned short*)outv)[(long long)grow * 128 + gcol] = f2b(v);
                    else
                        ((float*)outv)[(long long)grow * 128 + gcol] = v;
                }
            }
        }
    }
}

extern "C" void kernel_launch(void* const* d_in, const int* in_sizes, int n_in,
                              void* d_out, int out_size, void* d_ws, size_t ws_size,
                              hipStream_t stream) {
    const float* feat = (const float*)d_in[0];
    const int*   edges = (const int*)d_in[1];
    const float* W1 = (const float*)d_in[2];
    const float* b1 = (const float*)d_in[3];
    const float* W2 = (const float*)d_in[4];
    const float* b2 = (const float*)d_in[5];
    float* out = (float*)d_out;

    const int N = in_sizes[0] / 128;
    const int E = in_sizes[1] / 2;
    const int* src = edges;
    const int* dst = edges + E;
    const int B = (N + (1 << BSHIFT) - 1) >> BSHIFT;

    // Workspace layout (segments padded to 32B):
    unsigned short* featb = (unsigned short*)d_ws;
    unsigned short* Hb    = featb + (size_t)N * 128;
    unsigned*       pairs = (unsigned*)Hb;          // dead before aggregate-1
    unsigned short* Wt1   = Hb + (size_t)N * 128;
    unsigned short* Wt2   = Wt1 + 128 * 128;
    int* offsets = (int*)(Wt2 + 128 * 128);
    int* bcursor = offsets + ((N + 8) & ~7);
    int* bstart  = bcursor + 512;
    int* csr     = bstart + 512;
    int* bpart   = csr + ((E + 8) & ~7);            // BMAX*HB ints = 512 KB

    const long long nfeat = (long long)N * 128;
    const int nf4 = (int)((nfeat / 4 + 255) / 256);

    // ---- fused front: cvt_feat + cvt_w + bucket-hist partials ----
    front_kernel<<<nf4 + 64 + HB, 256, 0, stream>>>(feat, featb, nfeat, W1, W2,
                                                    Wt1, Wt2, dst, bpart, E, B, nf4);
    // ---- CSR build ----
    bscan_kernel<<<1, 512, 0, stream>>>(bpart, bcursor, bstart, B);
    bscatter_kernel<<<256, 256, 0, stream>>>(src, dst, bcursor, pairs, E, B);
    bfinal_kernel<<<B, 256, 0, stream>>>(pairs, bstart, offsets, csr, N, E);

    const int aggGrid = (N + 3) / 4;
    const int gemmGrid = (N + 127) / 128;

    // ---- Layer 1: aggregate bf16 -> Hb; GEMM writes h1 bf16 into featb ----
    aggregate_kernel<<<aggGrid, 256, 0, stream>>>(featb, offsets, csr, Hb, N);
    gemm_mfma<true><<<gemmGrid, 256, 0, stream>>>(Hb, Wt1, b1, (void*)featb, N);

    // ---- Layer 2: aggregate h1b -> Hb; GEMM writes fp32 to d_out ----
    aggregate_kernel<<<aggGrid, 256, 0, stream>>>(featb, offsets, csr, Hb, N);
    gemm_mfma<false><<<gemmGrid, 256, 0, stream>>>(Hb, Wt2, b2, (void*)out, N);
}